// Round 4
// baseline (46.782 us; speedup 1.0000x reference)
//
#include <hip/hip_runtime.h>

// SparsityLoss: out = THETA * sum(where(valid, masks, 0)) / (I*(J-1)*K)
// I=128, J=49, K=4096 -> n = 25,690,112 elements.
// masks: fp32 (102.8 MB). valid: int32 (102.8 MB).
// Round-3 evidence: inputs L3-resident on warm replays (hbm_bytes~0), VALUBusy
// 4%, effective read BW ~5.7 TB/s. Hypothesis: zero-reuse stream through L2
// wastes allocation bandwidth -> use non-temporal loads to bypass L2 alloc.
// If flat, we are at the XCD-fabric streaming ceiling (~6 TB/s) = roofline.

static constexpr double kTheta = 0.0001;
static constexpr int kI = 128;
static constexpr int kJ = 49;
static constexpr int kK = 4096;
static constexpr int kBlocks = 2048;     // 8 blocks/CU * 256 CUs = exact fill
static constexpr int kBlockSize = 256;

typedef float f32x4 __attribute__((ext_vector_type(4)));
typedef int i32x4 __attribute__((ext_vector_type(4)));

__global__ __launch_bounds__(kBlockSize) void sparsity_partial_kernel(
    const f32x4* __restrict__ masks4,
    const i32x4* __restrict__ valid4,
    double* __restrict__ block_sums,
    int n4,
    const float* __restrict__ masks_tail,
    const int* __restrict__ valid_tail,
    int n_tail) {
    const int tid = blockIdx.x * blockDim.x + threadIdx.x;
    const int stride = gridDim.x * blockDim.x;

    double local = 0.0;
    int i = tid;
    // 4x unrolled grid-stride loop, non-temporal (L2-bypass) loads.
    for (; i + 3 * stride < n4; i += 4 * stride) {
        f32x4 m0 = __builtin_nontemporal_load(&masks4[i]);
        f32x4 m1 = __builtin_nontemporal_load(&masks4[i + stride]);
        f32x4 m2 = __builtin_nontemporal_load(&masks4[i + 2 * stride]);
        f32x4 m3 = __builtin_nontemporal_load(&masks4[i + 3 * stride]);
        i32x4 v0 = __builtin_nontemporal_load(&valid4[i]);
        i32x4 v1 = __builtin_nontemporal_load(&valid4[i + stride]);
        i32x4 v2 = __builtin_nontemporal_load(&valid4[i + 2 * stride]);
        i32x4 v3 = __builtin_nontemporal_load(&valid4[i + 3 * stride]);
        float s0 = (v0.x ? m0.x : 0.0f) + (v0.y ? m0.y : 0.0f) +
                   (v0.z ? m0.z : 0.0f) + (v0.w ? m0.w : 0.0f);
        float s1 = (v1.x ? m1.x : 0.0f) + (v1.y ? m1.y : 0.0f) +
                   (v1.z ? m1.z : 0.0f) + (v1.w ? m1.w : 0.0f);
        float s2 = (v2.x ? m2.x : 0.0f) + (v2.y ? m2.y : 0.0f) +
                   (v2.z ? m2.z : 0.0f) + (v2.w ? m2.w : 0.0f);
        float s3 = (v3.x ? m3.x : 0.0f) + (v3.y ? m3.y : 0.0f) +
                   (v3.z ? m3.z : 0.0f) + (v3.w ? m3.w : 0.0f);
        local += (double)s0 + (double)s1 + (double)s2 + (double)s3;
    }
    for (; i < n4; i += stride) {
        f32x4 m = __builtin_nontemporal_load(&masks4[i]);
        i32x4 v = __builtin_nontemporal_load(&valid4[i]);
        float s = (v.x ? m.x : 0.0f) + (v.y ? m.y : 0.0f) +
                  (v.z ? m.z : 0.0f) + (v.w ? m.w : 0.0f);
        local += (double)s;
    }
    // Scalar tail (n % 4): empty for n = 25,690,112.
    if (blockIdx.x == 0 && threadIdx.x == 0) {
        for (int t = 0; t < n_tail; ++t) {
            if (valid_tail[t]) local += (double)masks_tail[t];
        }
    }

    // Wave-64 shuffle reduction.
    for (int off = 32; off > 0; off >>= 1) {
        local += __shfl_down(local, off, 64);
    }
    __shared__ double wave_sums[kBlockSize / 64];
    const int lane = threadIdx.x & 63;
    const int wid = threadIdx.x >> 6;
    if (lane == 0) wave_sums[wid] = local;
    __syncthreads();
    if (threadIdx.x == 0) {
        double s = wave_sums[0] + wave_sums[1] + wave_sums[2] + wave_sums[3];
        block_sums[blockIdx.x] = s;   // plain store, no atomics
    }
}

__global__ __launch_bounds__(64) void sparsity_finalize_kernel(
    const double* __restrict__ block_sums, int nblocks,
    float* __restrict__ out) {
    double local = 0.0;
    for (int i = threadIdx.x; i < nblocks; i += 64) {
        local += block_sums[i];
    }
    for (int off = 32; off > 0; off >>= 1) {
        local += __shfl_down(local, off, 64);
    }
    if (threadIdx.x == 0) {
        const double denom = (double)kI * (double)(kJ - 1) * (double)kK;
        out[0] = (float)(kTheta * local / denom);
    }
}

extern "C" void kernel_launch(void* const* d_in, const int* in_sizes, int n_in,
                              void* d_out, int out_size, void* d_ws, size_t ws_size,
                              hipStream_t stream) {
    const float* masks = (const float*)d_in[0];
    const int* valid = (const int*)d_in[1];
    const int n = in_sizes[0];

    const int n4 = n / 4;
    const int n_tail = n - n4 * 4;

    double* block_sums = (double*)d_ws;  // kBlocks doubles = 16 KB scratch

    sparsity_partial_kernel<<<kBlocks, kBlockSize, 0, stream>>>(
        (const f32x4*)masks, (const i32x4*)valid, block_sums, n4,
        masks + n4 * 4, valid + n4 * 4, n_tail);

    sparsity_finalize_kernel<<<1, 64, 0, stream>>>(
        block_sums, kBlocks, (float*)d_out);
}

// Round 5
// 40.142 us; speedup vs baseline: 1.1654x; 1.1654x over previous
//
#include <hip/hip_runtime.h>

// SparsityLoss: out = THETA * sum(where(valid, masks, 0)) / (I*(J-1)*K)
// I=128, J=49, K=4096 -> n = 25,690,112 elements.
// masks: fp32 (102.8 MB). valid: int32 (102.8 MB). Total 205.6 MB, zero reuse.
// Round-4 post-mortem: nt loads REGRESSED (41.2 -> 46.8 us; L3 retention lost).
// Reverted. Round-3 state = 5.7 TB/s effective from L3 (91% of 6.29 TB/s
// streaming ceiling). This round: deepen MLP (6x unroll, 12 loads in flight,
// VGPR=24 showed compiler had serialized the old loop) + keep L3-friendly
// regular loads. If flat vs round 3 -> fabric-BW roofline.

static constexpr double kTheta = 0.0001;
static constexpr int kI = 128;
static constexpr int kJ = 49;
static constexpr int kK = 4096;
static constexpr int kBlocks = 2048;     // 8 blocks/CU * 256 CUs
static constexpr int kBlockSize = 256;
static constexpr int kUnroll = 6;        // 12 x 16B loads in flight per thread

typedef float f32x4 __attribute__((ext_vector_type(4)));
typedef int i32x4 __attribute__((ext_vector_type(4)));

__global__ __launch_bounds__(kBlockSize) void sparsity_partial_kernel(
    const f32x4* __restrict__ masks4,
    const i32x4* __restrict__ valid4,
    double* __restrict__ block_sums,
    int n4,
    const float* __restrict__ masks_tail,
    const int* __restrict__ valid_tail,
    int n_tail) {
    const int tid = blockIdx.x * blockDim.x + threadIdx.x;
    const int stride = gridDim.x * blockDim.x;

    double local = 0.0;
    int i = tid;
    // Fully-unrolled 6-wide grid-stride loop: all indices compile-time
    // constant (rule: runtime-indexed arrays spill to scratch).
    for (; i + (kUnroll - 1) * stride < n4; i += kUnroll * stride) {
        f32x4 m[kUnroll];
        i32x4 v[kUnroll];
#pragma unroll
        for (int k = 0; k < kUnroll; ++k) m[k] = masks4[i + k * stride];
#pragma unroll
        for (int k = 0; k < kUnroll; ++k) v[k] = valid4[i + k * stride];
        float s = 0.0f;
        double part = 0.0;
#pragma unroll
        for (int k = 0; k < kUnroll; ++k) {
            float sk = (v[k].x ? m[k].x : 0.0f) + (v[k].y ? m[k].y : 0.0f) +
                       (v[k].z ? m[k].z : 0.0f) + (v[k].w ? m[k].w : 0.0f);
            part += (double)sk;
        }
        (void)s;
        local += part;
    }
    // Remainder strides (<= kUnroll-1 per thread).
    for (; i < n4; i += stride) {
        f32x4 m = masks4[i];
        i32x4 v = valid4[i];
        float sk = (v.x ? m.x : 0.0f) + (v.y ? m.y : 0.0f) +
                   (v.z ? m.z : 0.0f) + (v.w ? m.w : 0.0f);
        local += (double)sk;
    }
    // Scalar tail (n % 4): empty for n = 25,690,112.
    if (blockIdx.x == 0 && threadIdx.x == 0) {
        for (int t = 0; t < n_tail; ++t) {
            if (valid_tail[t]) local += (double)masks_tail[t];
        }
    }

    // Wave-64 shuffle reduction.
    for (int off = 32; off > 0; off >>= 1) {
        local += __shfl_down(local, off, 64);
    }
    __shared__ double wave_sums[kBlockSize / 64];
    const int lane = threadIdx.x & 63;
    const int wid = threadIdx.x >> 6;
    if (lane == 0) wave_sums[wid] = local;
    __syncthreads();
    if (threadIdx.x == 0) {
        double s = wave_sums[0] + wave_sums[1] + wave_sums[2] + wave_sums[3];
        block_sums[blockIdx.x] = s;   // plain store, no atomics
    }
}

__global__ __launch_bounds__(kBlockSize) void sparsity_finalize_kernel(
    const double* __restrict__ block_sums, int nblocks,
    float* __restrict__ out) {
    double local = 0.0;
    for (int i = threadIdx.x; i < nblocks; i += kBlockSize) {
        local += block_sums[i];
    }
    for (int off = 32; off > 0; off >>= 1) {
        local += __shfl_down(local, off, 64);
    }
    __shared__ double wave_sums[kBlockSize / 64];
    const int lane = threadIdx.x & 63;
    const int wid = threadIdx.x >> 6;
    if (lane == 0) wave_sums[wid] = local;
    __syncthreads();
    if (threadIdx.x == 0) {
        double s = wave_sums[0] + wave_sums[1] + wave_sums[2] + wave_sums[3];
        const double denom = (double)kI * (double)(kJ - 1) * (double)kK;
        out[0] = (float)(kTheta * s / denom);
    }
}

extern "C" void kernel_launch(void* const* d_in, const int* in_sizes, int n_in,
                              void* d_out, int out_size, void* d_ws, size_t ws_size,
                              hipStream_t stream) {
    const float* masks = (const float*)d_in[0];
    const int* valid = (const int*)d_in[1];
    const int n = in_sizes[0];

    const int n4 = n / 4;
    const int n_tail = n - n4 * 4;

    double* block_sums = (double*)d_ws;  // kBlocks doubles = 16 KB scratch

    sparsity_partial_kernel<<<kBlocks, kBlockSize, 0, stream>>>(
        (const f32x4*)masks, (const i32x4*)valid, block_sums, n4,
        masks + n4 * 4, valid + n4 * 4, n_tail);

    sparsity_finalize_kernel<<<1, kBlockSize, 0, stream>>>(
        block_sums, kBlocks, (float*)d_out);
}